// Round 3
// baseline (168.985 us; speedup 1.0000x reference)
//
#include <hip/hip_runtime.h>

// Problem constants (from reference)
#define VOCAB 50000
#define SEQ   2048
#define BATCH 64
#define DIM   256
#define NC    16              // chunks over SEQ for pooling
#define CHUNK (SEQ / NC)      // 128
#define H1    100
#define H2    150
#define HASH  4096            // per-row hash table (load factor <= 0.5)

// ---------------------------------------------------------------------------
// Kernel 1: per-row tf counts + tf*idf scores via LDS hash histogram.
// One block per batch row. Insert 2048 tokens (atomicCAS open addressing),
// then look up counts.
// ---------------------------------------------------------------------------
__global__ __launch_bounds__(1024)
void k_scores(const int* __restrict__ x,
              const float* __restrict__ idf,
              float* __restrict__ scores) {
    __shared__ int   tok[SEQ];
    __shared__ int   hkey[HASH];
    __shared__ int   hcnt[HASH];
    const int b = blockIdx.x;
    const int t = threadIdx.x;            // 0..1023

    for (int i = t; i < HASH; i += 1024) { hkey[i] = -1; hcnt[i] = 0; }
    for (int s = t; s < SEQ; s += 1024)  tok[s] = x[s * BATCH + b];
    __syncthreads();

    // insert phase
    for (int s = t; s < SEQ; s += 1024) {
        const int mytok = tok[s];
        unsigned h = ((unsigned)mytok * 2654435761u) >> 20;   // top 12 bits
        while (true) {
            int prev = atomicCAS(&hkey[h], -1, mytok);
            if (prev == -1 || prev == mytok) { atomicAdd(&hcnt[h], 1); break; }
            h = (h + 1) & (HASH - 1);
        }
    }
    __syncthreads();

    // lookup phase
    for (int s = t; s < SEQ; s += 1024) {
        const int mytok = tok[s];
        unsigned h = ((unsigned)mytok * 2654435761u) >> 20;
        while (hkey[h] != mytok) h = (h + 1) & (HASH - 1);
        float sc = (mytok == 0) ? 0.0f : (float)hcnt[h] * idf[mytok];
        scores[b * SEQ + s] = sc;
    }
}

// ---------------------------------------------------------------------------
// Kernel 2: pooled partials, float4 gather.
// Block = 256 threads = 4 waves. Each wave covers all 256 dims (64 lanes x
// float4) and a quarter of the chunk's s-positions; cross-wave reduce in LDS.
// ---------------------------------------------------------------------------
__global__ __launch_bounds__(256)
void k_pool(const int* __restrict__ x,
            const float* __restrict__ emb,
            const float* __restrict__ scores,
            float* __restrict__ partials) {
    __shared__ int   tok[CHUNK];
    __shared__ float sc[CHUNK];
    __shared__ float acc_lds[4][DIM];
    const int c = blockIdx.x;
    const int b = blockIdx.y;
    const int t = threadIdx.x;            // 0..255
    const int wave = t >> 6, lane = t & 63;
    const int s0 = c * CHUNK;

    if (t < CHUNK) {
        tok[t] = x[(s0 + t) * BATCH + b];
        sc[t]  = scores[b * SEQ + s0 + t];
    }
    __syncthreads();

    float4 acc = make_float4(0.f, 0.f, 0.f, 0.f);
    for (int i = wave; i < CHUNK; i += 4) {
        const float s = sc[i];
        const float4 v = ((const float4*)(emb + (size_t)tok[i] * DIM))[lane];
        acc.x = fmaf(v.x, s, acc.x);
        acc.y = fmaf(v.y, s, acc.y);
        acc.z = fmaf(v.z, s, acc.z);
        acc.w = fmaf(v.w, s, acc.w);
    }
    ((float4*)acc_lds[wave])[lane] = acc;
    __syncthreads();

    if (t < DIM) {
        float r = acc_lds[0][t] + acc_lds[1][t] + acc_lds[2][t] + acc_lds[3][t];
        partials[((size_t)c * BATCH + b) * DIM + t] = r;
    }
}

// ---------------------------------------------------------------------------
// Kernel 3a: reduce partials -> pooledT (LDS), then stage-1 neurons.
// lane = batch row b; weights via wave-uniform scalar loads; no shuffles.
// Grid: 4 blocks x 1024 threads; block bx owns neurons [25*bx, 25*bx+25).
// Writes h1T[j][b] (global ws).
// ---------------------------------------------------------------------------
#define PT_LD 65   // padded row stride for pooledT[d][b] to avoid bank conflicts
__global__ __launch_bounds__(1024)
void k_mlp1(const float* __restrict__ partials,
            const float* __restrict__ W1, const float* __restrict__ b1,
            float* __restrict__ h1T) {
    __shared__ float pooledT[DIM * PT_LD];   // [d][b], padded: 66.6 KB
    const int t = threadIdx.x;               // 0..1023
    const int w = t >> 6, lane = t & 63;     // lane = batch row b
    const int base = 25 * blockIdx.x;

    // reduce partials over c: flat i = b*DIM + d, coalesced reads
#pragma unroll
    for (int n = 0; n < 16; ++n) {
        const int i = n * 1024 + t;          // covers 16384 = BATCH*DIM
        const int b = i >> 8, d = i & 255;
        float a = 0.0f;
#pragma unroll
        for (int c = 0; c < NC; ++c)
            a += partials[c * (BATCH * DIM) + i];
        pooledT[d * PT_LD + b] = a;          // stride 65: conflict-free
    }
    __syncthreads();

    // stage 1: wave w computes neurons j0 = base+w and j1 = base+16+w (if valid)
    {
        const int j0 = __builtin_amdgcn_readfirstlane(base + w);
        const bool has1 = (16 + w) < 25;
        const int j1 = __builtin_amdgcn_readfirstlane(base + ((16 + w) < 25 ? 16 + w : 0));
        float a0 = 0.0f, a1 = 0.0f;
#pragma unroll 8
        for (int k = 0; k < DIM; ++k) {
            const float v = pooledT[k * PT_LD + lane];   // 2 lanes/bank: free
            a0 = fmaf(v, W1[j0 * DIM + k], a0);          // s_load (uniform)
            a1 = fmaf(v, W1[j1 * DIM + k], a1);
        }
        h1T[j0 * BATCH + lane] = fmaxf(a0 + b1[j0], 0.0f);
        if (has1) h1T[j1 * BATCH + lane] = fmaxf(a1 + b1[j1], 0.0f);
    }
}

// ---------------------------------------------------------------------------
// Kernel 3b: stage 2 + stage 3 + softmax.  One block x 1024 threads.
// h1 staged to LDS; lane = b; wave w owns up to 10 stage-2 neurons.
// ---------------------------------------------------------------------------
__global__ __launch_bounds__(1024)
void k_mlp2(const float* __restrict__ h1T,
            const float* __restrict__ W2, const float* __restrict__ b2,
            const float* __restrict__ W3, const float* __restrict__ b3,
            float* __restrict__ out) {
    __shared__ float h1s[H1 * BATCH];    // [k][b]  25.6 KB
    __shared__ float h2s[H2 * BATCH];    // [j][b]  38.4 KB
    __shared__ float lg[2][BATCH];
    const int t = threadIdx.x;
    const int w = t >> 6, lane = t & 63; // lane = batch row b

    for (int i = t; i < H1 * BATCH; i += 1024) h1s[i] = h1T[i];
    __syncthreads();

    // stage 2: wave w -> neurons j = w + 16*i, i = 0..9 (clamped; 7% waste)
    {
        float acc[10];
        int   jj[10];
        bool  valid[10];
#pragma unroll
        for (int i = 0; i < 10; ++i) {
            const int j = w + 16 * i;
            valid[i] = (j < H2);
            jj[i] = __builtin_amdgcn_readfirstlane(valid[i] ? j : 0);
            acc[i] = 0.0f;
        }
#pragma unroll 4
        for (int k = 0; k < H1; ++k) {
            const float v = h1s[k * BATCH + lane];
#pragma unroll
            for (int i = 0; i < 10; ++i)
                acc[i] = fmaf(v, W2[jj[i] * H1 + k], acc[i]);
        }
#pragma unroll
        for (int i = 0; i < 10; ++i)
            if (valid[i]) h2s[jj[i] * BATCH + lane] = fmaxf(acc[i] + b2[jj[i]], 0.0f);
    }
    __syncthreads();

    // stage 3: waves 0,1 compute logits
    if (w < 2) {
        const int j = __builtin_amdgcn_readfirstlane(w);
        float a = 0.0f;
#pragma unroll 5
        for (int k = 0; k < H2; ++k)
            a = fmaf(h2s[k * BATCH + lane], W3[j * H2 + k], a);
        lg[j][lane] = a + b3[j];
    }
    __syncthreads();

    if (t < BATCH) {
        const float l0 = lg[0][t], l1 = lg[1][t];
        const float m  = fmaxf(l0, l1);
        const float e0 = __expf(l0 - m);
        const float e1 = __expf(l1 - m);
        const float inv = 1.0f / (e0 + e1);
        out[t * 2 + 0] = e0 * inv;
        out[t * 2 + 1] = e1 * inv;
    }
}

// ---------------------------------------------------------------------------
extern "C" void kernel_launch(void* const* d_in, const int* in_sizes, int n_in,
                              void* d_out, int out_size, void* d_ws, size_t ws_size,
                              hipStream_t stream) {
    const int*   x   = (const int*)  d_in[0];   // [SEQ, BATCH] int32
    const float* emb = (const float*)d_in[1];   // [VOCAB, DIM]
    const float* idf = (const float*)d_in[2];   // [VOCAB]
    const float* W1  = (const float*)d_in[3];   // [H1, DIM]
    const float* b1  = (const float*)d_in[4];   // [H1]
    const float* W2  = (const float*)d_in[5];   // [H2, H1]
    const float* b2  = (const float*)d_in[6];   // [H2]
    const float* W3  = (const float*)d_in[7];   // [2, H2]
    const float* b3  = (const float*)d_in[8];   // [2]
    float* out = (float*)d_out;                 // [BATCH, 2]

    // workspace layout
    float* scores   = (float*)d_ws;                         // BATCH*SEQ    = 512 KB
    float* partials = scores + (size_t)BATCH * SEQ;         // NC*BATCH*DIM = 1 MB
    float* h1T      = partials + (size_t)NC * BATCH * DIM;  // H1*BATCH     = 25.6 KB

    k_scores<<<BATCH, 1024, 0, stream>>>(x, idf, scores);
    k_pool  <<<dim3(NC, BATCH), 256, 0, stream>>>(x, emb, scores, partials);
    k_mlp1  <<<4, 1024, 0, stream>>>(partials, W1, b1, h1T);
    k_mlp2  <<<1, 1024, 0, stream>>>(h1T, W2, b2, W3, b3, out);
}

// Round 4
// 129.415 us; speedup vs baseline: 1.3058x; 1.3058x over previous
//
#include <hip/hip_runtime.h>

// Problem constants (from reference)
#define VOCAB 50000
#define SEQ   2048
#define BATCH 64
#define DIM   256
#define H1    100
#define H2    150
#define HASH  4096            // per-row hash table (load factor <= 0.5)
#define NW    16              // waves per block (1024 threads)

// ---------------------------------------------------------------------------
// ONE kernel: the whole pipeline is independent per batch row b.
//   phase 1: load row tokens -> LDS
//   phase 2: tf histogram via LDS hash (atomicCAS open addressing)
//   phase 3: scores[s] = tok==0 ? 0 : tf * idf[tok]
//   phase 4: pooled[d] = sum_s emb[tok_s][d] * scores[s]   (float4 gather,
//            per-wave register accumulate, cross-wave LDS reduce)
//   phase 5: 3-layer MLP + softmax, all in LDS (no reductions across waves:
//            4 threads per neuron + tiny 4-way LDS combine)
// Grid: 64 blocks x 1024 threads. No workspace, no inter-kernel launches.
// ---------------------------------------------------------------------------
__global__ __launch_bounds__(1024)
void k_fused(const int* __restrict__ x,
             const float* __restrict__ emb,
             const float* __restrict__ idf,
             const float* __restrict__ W1, const float* __restrict__ b1,
             const float* __restrict__ W2, const float* __restrict__ b2,
             const float* __restrict__ W3, const float* __restrict__ b3,
             float* __restrict__ out) {
    __shared__ int   tok[SEQ];        //  8 KB
    __shared__ int   hkey[HASH];      // 16 KB
    __shared__ int   hcnt[HASH];      // 16 KB
    __shared__ float sc[SEQ];         //  8 KB
    __shared__ float wacc[NW][DIM];   // 16 KB per-wave pooled partials
    __shared__ float pooled[DIM];     //  1 KB
    __shared__ float hp1[128][4];     //  2 KB stage-1 partials
    __shared__ float h1s[H1];
    __shared__ float hp2[H2][4];      //  2.4 KB stage-2 partials
    __shared__ float h2s[H2];
    __shared__ float lg[2];

    const int b = blockIdx.x;
    const int t = threadIdx.x;            // 0..1023
    const int w = t >> 6, lane = t & 63;

    // ---- phase 1: row tokens + hash init ----
    for (int i = t; i < HASH; i += 1024) { hkey[i] = -1; hcnt[i] = 0; }
#pragma unroll
    for (int n = 0; n < SEQ / 1024; ++n) {
        const int s = n * 1024 + t;
        tok[s] = x[s * BATCH + b];
    }
    __syncthreads();

    // ---- phase 2: histogram insert ----
#pragma unroll
    for (int n = 0; n < SEQ / 1024; ++n) {
        const int s = n * 1024 + t;
        const int mytok = tok[s];
        unsigned h = ((unsigned)mytok * 2654435761u) >> 20;   // top 12 bits
        while (true) {
            int prev = atomicCAS(&hkey[h], -1, mytok);
            if (prev == -1 || prev == mytok) { atomicAdd(&hcnt[h], 1); break; }
            h = (h + 1) & (HASH - 1);
        }
    }
    __syncthreads();

    // ---- phase 3: scores ----
#pragma unroll
    for (int n = 0; n < SEQ / 1024; ++n) {
        const int s = n * 1024 + t;
        const int mytok = tok[s];
        unsigned h = ((unsigned)mytok * 2654435761u) >> 20;
        while (hkey[h] != mytok) h = (h + 1) & (HASH - 1);
        sc[s] = (mytok == 0) ? 0.0f : (float)hcnt[h] * idf[mytok];
    }
    __syncthreads();

    // ---- phase 4: tf-idf weighted embedding pool ----
    {
        const float4* embv = (const float4*)emb;     // emb row = 64 float4
        float4 acc = make_float4(0.f, 0.f, 0.f, 0.f);
        const int s0 = w * (SEQ / NW);
#pragma unroll 4
        for (int i = 0; i < SEQ / NW; ++i) {
            const int s = s0 + i;
            const float sv = sc[s];                  // LDS broadcast
            const float4 v = embv[(size_t)tok[s] * (DIM / 4) + lane];
            acc.x = fmaf(v.x, sv, acc.x);
            acc.y = fmaf(v.y, sv, acc.y);
            acc.z = fmaf(v.z, sv, acc.z);
            acc.w = fmaf(v.w, sv, acc.w);
        }
        ((float4*)wacc[w])[lane] = acc;
    }
    __syncthreads();

    if (t < DIM) {
        float a = 0.0f;
#pragma unroll
        for (int i = 0; i < NW; ++i) a += wacc[i][t];
        pooled[t] = a;
    }
    __syncthreads();

    // ---- phase 5a: stage 1 (100 neurons, k=256). 4 threads/neuron. ----
    if (t < 512) {
        const int j = t >> 2;                 // 0..127 (j<100 active)
        const int q = t & 3;                  // k-quarter
        if (j < H1) {
            const float4* wv = (const float4*)(W1 + j * DIM + q * 64);
            const float4* pv = (const float4*)(pooled) + q * 16;
            float a = 0.0f;
#pragma unroll
            for (int i = 0; i < 16; ++i) {
                const float4 ww = wv[i];
                const float4 pp = pv[i];      // broadcast within same-q group
                a += ww.x * pp.x + ww.y * pp.y + ww.z * pp.z + ww.w * pp.w;
            }
            hp1[j][q] = a;
        }
    }
    __syncthreads();
    if (t < H1)
        h1s[t] = fmaxf(hp1[t][0] + hp1[t][1] + hp1[t][2] + hp1[t][3] + b1[t], 0.0f);
    __syncthreads();

    // ---- phase 5b: stage 2 (150 neurons, k=100). 4 threads/neuron. ----
    if (t < 600) {
        const int j = t >> 2;                 // 0..149
        const int q = t & 3;                  // k-chunk of 25
        const float* wv = W2 + j * H1 + q * 25;
        float a = 0.0f;
#pragma unroll
        for (int i = 0; i < 25; ++i)
            a = fmaf(wv[i], h1s[q * 25 + i], a);
        hp2[j][q] = a;
    }
    __syncthreads();
    if (t < H2)
        h2s[t] = fmaxf(hp2[t][0] + hp2[t][1] + hp2[t][2] + hp2[t][3] + b2[t], 0.0f);
    __syncthreads();

    // ---- phase 5c: logits + softmax ----
    if (t < 2) {
        const float* wv = W3 + t * H2;
        float a = b3[t];
        for (int k = 0; k < H2; ++k) a = fmaf(wv[k], h2s[k], a);
        lg[t] = a;
    }
    __syncthreads();
    if (t == 0) {
        const float m  = fmaxf(lg[0], lg[1]);
        const float e0 = __expf(lg[0] - m);
        const float e1 = __expf(lg[1] - m);
        const float inv = 1.0f / (e0 + e1);
        out[b * 2 + 0] = e0 * inv;
        out[b * 2 + 1] = e1 * inv;
    }
}

// ---------------------------------------------------------------------------
extern "C" void kernel_launch(void* const* d_in, const int* in_sizes, int n_in,
                              void* d_out, int out_size, void* d_ws, size_t ws_size,
                              hipStream_t stream) {
    const int*   x   = (const int*)  d_in[0];   // [SEQ, BATCH] int32
    const float* emb = (const float*)d_in[1];   // [VOCAB, DIM]
    const float* idf = (const float*)d_in[2];   // [VOCAB]
    const float* W1  = (const float*)d_in[3];   // [H1, DIM]
    const float* b1  = (const float*)d_in[4];   // [H1]
    const float* W2  = (const float*)d_in[5];   // [H2, H1]
    const float* b2  = (const float*)d_in[6];   // [H2]
    const float* W3  = (const float*)d_in[7];   // [2, H2]
    const float* b3  = (const float*)d_in[8];   // [2]
    float* out = (float*)d_out;                 // [BATCH, 2]

    k_fused<<<BATCH, 1024, 0, stream>>>(x, emb, idf, W1, b1, W2, b2, W3, b3, out);
}